// Round 1
// baseline (148.441 us; speedup 1.0000x reference)
//
#include <hip/hip_runtime.h>
#include <hip/hip_bf16.h>

// Attention_15564961480846: q/k/v projections + softmax(QK^T/8)V
// B=4, S=4096, D_MODEL=128, d_k=d_v=64.
// Round 0: correctness-first bf16 MFMA flash attention.

using f32x4 = __attribute__((ext_vector_type(4))) float;
using s16x8 = __attribute__((ext_vector_type(8))) short;
using s16x4 = __attribute__((ext_vector_type(4))) short;

#define MFMA_BF16(a, b, c) __builtin_amdgcn_mfma_f32_16x16x32_bf16((a), (b), (c), 0, 0, 0)

constexpr int SEQ = 4096;
constexpr int DM  = 128;   // d_model
constexpr int DV  = 64;    // d_k = d_v

static __device__ __forceinline__ unsigned short f2bf(float f) {
  union { float f; unsigned u; } x; x.f = f;
  unsigned r = x.u + 0x7fffu + ((x.u >> 16) & 1u);   // RNE
  return (unsigned short)(r >> 16);
}

// ---------------------------------------------------------------------------
// Projection: out = in[16384x128] @ W[128x64] + b, stored bf16.
// q additionally scaled by 1/8 (folds softmax scale into Q).
// Per block: 64 rows (4 waves x 16). Weights staged transposed in LDS (bf16).
// ---------------------------------------------------------------------------
__global__ __launch_bounds__(256) void proj_kernel(
    const float* __restrict__ q_in, const float* __restrict__ k_in,
    const float* __restrict__ v_in,
    const float* __restrict__ Wq, const float* __restrict__ bq,
    const float* __restrict__ Wk, const float* __restrict__ bk,
    const float* __restrict__ Wv, const float* __restrict__ bv,
    unsigned short* __restrict__ qp, unsigned short* __restrict__ kp,
    unsigned short* __restrict__ vp)
{
  // Wt[m][col][k], k-stride 136 (mult of 8 -> 16B aligned rows; bank spread)
  __shared__ unsigned short Wt[3][64][136];
  const int tid = threadIdx.x;
  {
    const float* Ws[3] = {Wq, Wk, Wv};
    for (int m = 0; m < 3; ++m) {
      const float* W = Ws[m];
      for (int idx = tid; idx < DM * DV; idx += 256) {
        const int k = idx >> 6, c = idx & 63;   // W[k][c]
        Wt[m][c][k] = f2bf(W[idx]);
      }
    }
  }
  __syncthreads();

  const int w = tid >> 6, l = tid & 63;
  const int lr = l & 15, lg = l >> 4;
  const int rowbase = blockIdx.x * 64 + w * 16;   // global row in [0,16384)

  const float* ins[3]  = {q_in, k_in, v_in};
  const float* bs[3]   = {bq, bk, bv};
  unsigned short* outs[3] = {qp, kp, vp};

  for (int m = 0; m < 3; ++m) {
    const float* in = ins[m];
    f32x4 acc[4] = {};
    #pragma unroll
    for (int ks = 0; ks < 4; ++ks) {            // k-window of 32 over DM=128
      const float* ap = in + (size_t)(rowbase + lr) * DM + ks * 32 + lg * 8;
      const float4 a0 = *(const float4*)ap;
      const float4 a1 = *(const float4*)(ap + 4);
      s16x8 af;
      af[0] = (short)f2bf(a0.x); af[1] = (short)f2bf(a0.y);
      af[2] = (short)f2bf(a0.z); af[3] = (short)f2bf(a0.w);
      af[4] = (short)f2bf(a1.x); af[5] = (short)f2bf(a1.y);
      af[6] = (short)f2bf(a1.z); af[7] = (short)f2bf(a1.w);
      #pragma unroll
      for (int nt = 0; nt < 4; ++nt) {
        const s16x8 bfm = *(const s16x8*)&Wt[m][nt * 16 + lr][ks * 32 + lg * 8];
        acc[nt] = MFMA_BF16(af, bfm, acc[nt]);
      }
    }
    const float* bias = bs[m];
    unsigned short* op = outs[m];
    const float scale = (m == 0) ? 0.125f : 1.0f;   // 1/sqrt(64) into q
    #pragma unroll
    for (int nt = 0; nt < 4; ++nt) {
      const int col = nt * 16 + lr;
      const float bb = bias[col];
      #pragma unroll
      for (int r = 0; r < 4; ++r) {
        const int row = rowbase + lg * 4 + r;
        op[(size_t)row * DV + col] = f2bf((acc[nt][r] + bb) * scale);
      }
    }
  }
}

// ---------------------------------------------------------------------------
// Flash attention: block = 4 waves x 16 q-rows (QB=64), KV tile = 64.
// K staged row-major [64][72] (padded); V staged transposed [d][key] [64][68];
// P re-laid out via per-wave LDS [16][72]. fp32 accum, online softmax.
// ---------------------------------------------------------------------------
__global__ __launch_bounds__(256) void attn_kernel(
    const unsigned short* __restrict__ qp, const unsigned short* __restrict__ kp,
    const unsigned short* __restrict__ vp, float* __restrict__ out)
{
  __shared__ unsigned short Kl[64][72];
  __shared__ unsigned short Vt[64][68];
  __shared__ unsigned short Pl[4][16][72];

  const int tid = threadIdx.x, w = tid >> 6, l = tid & 63;
  const int lr = l & 15, lg = l >> 4;
  const int b = blockIdx.y;
  const size_t boff = (size_t)b * SEQ * DV;
  const int qbase = blockIdx.x * 64 + w * 16;     // row within batch

  // Q fragments (A-operand): row = lr, k(d) = ks*32 + lg*8 .. +7
  s16x8 qf[2];
  #pragma unroll
  for (int ks = 0; ks < 2; ++ks)
    qf[ks] = *(const s16x8*)(qp + boff + (size_t)(qbase + lr) * DV + ks * 32 + lg * 8);

  f32x4 oacc[4] = {};
  float mrow[4], lrow[4];
  #pragma unroll
  for (int r = 0; r < 4; ++r) { mrow[r] = -1e30f; lrow[r] = 0.0f; }

  for (int kb = 0; kb < SEQ; kb += 64) {
    __syncthreads();   // prior iter's LDS reads done before restage
    const unsigned short* kg = kp + boff + (size_t)kb * DV;
    const unsigned short* vg = vp + boff + (size_t)kb * DV;
    #pragma unroll
    for (int pass = 0; pass < 2; ++pass) {
      const int idx = pass * 256 + tid;           // 512 x 16B = 8KB tile
      const int row = idx >> 3, dg = (idx & 7) * 8;
      *(s16x8*)&Kl[row][dg] = *(const s16x8*)(kg + row * DV + dg);
      const s16x8 vv = *(const s16x8*)(vg + row * DV + dg);
      #pragma unroll
      for (int j = 0; j < 8; ++j) Vt[dg + j][row] = (unsigned short)vv[j];
    }
    __syncthreads();

    // S = Q K^T  (S[q][key], col=key=lr within ntile, row=q=lg*4+r)
    f32x4 sacc[4] = {};
    #pragma unroll
    for (int ks = 0; ks < 2; ++ks) {
      #pragma unroll
      for (int nt = 0; nt < 4; ++nt) {
        const s16x8 bfm = *(const s16x8*)&Kl[nt * 16 + lr][ks * 32 + lg * 8];
        sacc[nt] = MFMA_BF16(qf[ks], bfm, sacc[nt]);
      }
    }

    // online softmax per q-row (rows lg*4+r, keys across 16 lanes x 4 ntiles)
    #pragma unroll
    for (int r = 0; r < 4; ++r) {
      float mx = fmaxf(fmaxf(sacc[0][r], sacc[1][r]), fmaxf(sacc[2][r], sacc[3][r]));
      #pragma unroll
      for (int sh = 1; sh < 16; sh <<= 1) mx = fmaxf(mx, __shfl_xor(mx, sh));
      const float mnew = fmaxf(mrow[r], mx);
      const float corr = exp2f((mrow[r] - mnew) * 1.44269504f);
      lrow[r] *= corr;
      #pragma unroll
      for (int nt = 0; nt < 4; ++nt) oacc[nt][r] *= corr;
      float ps = 0.0f;
      #pragma unroll
      for (int nt = 0; nt < 4; ++nt) {
        const float p = exp2f((sacc[nt][r] - mnew) * 1.44269504f);
        sacc[nt][r] = p; ps += p;
      }
      #pragma unroll
      for (int sh = 1; sh < 16; sh <<= 1) ps += __shfl_xor(ps, sh);
      lrow[r] += ps;
      mrow[r] = mnew;
    }

    // P -> LDS (bf16), transpose to A-operand layout
    #pragma unroll
    for (int nt = 0; nt < 4; ++nt)
      #pragma unroll
      for (int r = 0; r < 4; ++r)
        Pl[w][lg * 4 + r][nt * 16 + lr] = f2bf(sacc[nt][r]);
    __syncthreads();   // safe cross-lane visibility (round 0; optimize later)

    // O += P V   (A: row=q=lr, k=key; B: k=key, col=d=lr within ntile)
    #pragma unroll
    for (int ks = 0; ks < 2; ++ks) {
      const s16x8 af = *(const s16x8*)&Pl[w][lr][ks * 32 + lg * 8];
      #pragma unroll
      for (int nt = 0; nt < 4; ++nt) {
        const int dcol = nt * 16 + lr;
        const int k0 = ks * 32 + lg * 8;
        const s16x4 v0 = *(const s16x4*)&Vt[dcol][k0];
        const s16x4 v1 = *(const s16x4*)&Vt[dcol][k0 + 4];
        s16x8 bfm;
        bfm[0] = v0[0]; bfm[1] = v0[1]; bfm[2] = v0[2]; bfm[3] = v0[3];
        bfm[4] = v1[0]; bfm[5] = v1[1]; bfm[6] = v1[2]; bfm[7] = v1[3];
        oacc[nt] = MFMA_BF16(af, bfm, oacc[nt]);
      }
    }
  }

  float rl[4];
  #pragma unroll
  for (int r = 0; r < 4; ++r) rl[r] = 1.0f / lrow[r];
  #pragma unroll
  for (int nt = 0; nt < 4; ++nt)
    #pragma unroll
    for (int r = 0; r < 4; ++r) {
      const int row = qbase + lg * 4 + r;
      out[boff + (size_t)row * DV + nt * 16 + lr] = oacc[nt][r] * rl[r];
    }
}

extern "C" void kernel_launch(void* const* d_in, const int* in_sizes, int n_in,
                              void* d_out, int out_size, void* d_ws, size_t ws_size,
                              hipStream_t stream) {
  const float* q_in = (const float*)d_in[0];
  const float* k_in = (const float*)d_in[1];
  const float* v_in = (const float*)d_in[2];
  const float* Wq   = (const float*)d_in[3];
  const float* bq   = (const float*)d_in[4];
  const float* Wk   = (const float*)d_in[5];
  const float* bk   = (const float*)d_in[6];
  const float* Wv   = (const float*)d_in[7];
  const float* bv   = (const float*)d_in[8];

  unsigned short* qp = (unsigned short*)d_ws;
  unsigned short* kp = qp + (size_t)4 * SEQ * DV;
  unsigned short* vp = kp + (size_t)4 * SEQ * DV;
  float* out = (float*)d_out;

  proj_kernel<<<dim3(256), dim3(256), 0, stream>>>(
      q_in, k_in, v_in, Wq, bq, Wk, bk, Wv, bv, qp, kp, vp);
  attn_kernel<<<dim3(SEQ / 64, 4), dim3(256), 0, stream>>>(qp, kp, vp, out);
}

// Round 2
// 89.673 us; speedup vs baseline: 1.6553x; 1.6553x over previous
//
#include <hip/hip_runtime.h>
#include <hip/hip_bf16.h>

// Attention_15564961480846: q/k/v projections + softmax(QK^T/8)V
// B=4, S=4096, D_MODEL=128, d_k=d_v=64.
// Round 1: KV-split flash attention (occupancy 11.5% -> ~50%), V pre-transposed
// in proj (kills LDS scatter conflicts), per-wave P round-trip without barrier.

using f32x4 = __attribute__((ext_vector_type(4))) float;
using s16x8 = __attribute__((ext_vector_type(8))) short;
using s16x4 = __attribute__((ext_vector_type(4))) short;

#define MFMA_BF16(a, b, c) __builtin_amdgcn_mfma_f32_16x16x32_bf16((a), (b), (c), 0, 0, 0)

constexpr int SEQ = 4096;
constexpr int DM  = 128;   // d_model
constexpr int DV  = 64;    // d_k = d_v
constexpr int B_  = 4;

static __device__ __forceinline__ unsigned short f2bf(float f) {
  union { float f; unsigned u; } x; x.f = f;
  unsigned r = x.u + 0x7fffu + ((x.u >> 16) & 1u);   // RNE
  return (unsigned short)(r >> 16);
}

// ---------------------------------------------------------------------------
// Projection: out = in[16384x128] @ W[128x64] + b, stored bf16.
// q scaled by 1/8 (softmax scale folded in). v stored TRANSPOSED: vpT[b][d][s].
// ---------------------------------------------------------------------------
__global__ __launch_bounds__(256) void proj_kernel(
    const float* __restrict__ q_in, const float* __restrict__ k_in,
    const float* __restrict__ v_in,
    const float* __restrict__ Wq, const float* __restrict__ bq,
    const float* __restrict__ Wk, const float* __restrict__ bk,
    const float* __restrict__ Wv, const float* __restrict__ bv,
    unsigned short* __restrict__ qp, unsigned short* __restrict__ kp,
    unsigned short* __restrict__ vpT)
{
  __shared__ unsigned short Wt[3][64][136];
  const int tid = threadIdx.x;
  {
    const float* Ws[3] = {Wq, Wk, Wv};
    for (int m = 0; m < 3; ++m) {
      const float* W = Ws[m];
      for (int idx = tid; idx < DM * DV; idx += 256) {
        const int k = idx >> 6, c = idx & 63;   // W[k][c]
        Wt[m][c][k] = f2bf(W[idx]);
      }
    }
  }
  __syncthreads();

  const int w = tid >> 6, l = tid & 63;
  const int lr = l & 15, lg = l >> 4;
  const int rowbase = blockIdx.x * 64 + w * 16;   // global row in [0,16384)

  const float* ins[3]  = {q_in, k_in, v_in};
  const float* bs[3]   = {bq, bk, bv};

  for (int m = 0; m < 3; ++m) {
    const float* in = ins[m];
    f32x4 acc[4] = {};
    #pragma unroll
    for (int ks = 0; ks < 4; ++ks) {
      const float* ap = in + (size_t)(rowbase + lr) * DM + ks * 32 + lg * 8;
      const float4 a0 = *(const float4*)ap;
      const float4 a1 = *(const float4*)(ap + 4);
      s16x8 af;
      af[0] = (short)f2bf(a0.x); af[1] = (short)f2bf(a0.y);
      af[2] = (short)f2bf(a0.z); af[3] = (short)f2bf(a0.w);
      af[4] = (short)f2bf(a1.x); af[5] = (short)f2bf(a1.y);
      af[6] = (short)f2bf(a1.z); af[7] = (short)f2bf(a1.w);
      #pragma unroll
      for (int nt = 0; nt < 4; ++nt) {
        const s16x8 bfm = *(const s16x8*)&Wt[m][nt * 16 + lr][ks * 32 + lg * 8];
        acc[nt] = MFMA_BF16(af, bfm, acc[nt]);
      }
    }
    const float* bias = bs[m];
    const float scale = (m == 0) ? 0.125f : 1.0f;
    #pragma unroll
    for (int nt = 0; nt < 4; ++nt) {
      const int col = nt * 16 + lr;
      const float bb = bias[col];
      #pragma unroll
      for (int r = 0; r < 4; ++r) {
        const int row = rowbase + lg * 4 + r;
        const unsigned short val = f2bf((acc[nt][r] + bb) * scale);
        if (m == 0)      qp[(size_t)row * DV + col] = val;
        else if (m == 1) kp[(size_t)row * DV + col] = val;
        else             vpT[((size_t)(row >> 12) * DV + col) * SEQ + (row & (SEQ - 1))] = val;
      }
    }
  }
}

// ---------------------------------------------------------------------------
// Flash attention over a key slice [sp*klen, (sp+1)*klen).
// Block = 4 waves x 16 q-rows (QB=64). KV tile = 64.
// K staged [64][72]; V staged from vpT (already transposed) [64][72].
// If dout != nullptr (nsplit==1 path): normalize + write final output.
// Else: write unnormalized O partial + per-row m,l.
// ---------------------------------------------------------------------------
__global__ __launch_bounds__(256) void attn_split_kernel(
    const unsigned short* __restrict__ qp, const unsigned short* __restrict__ kp,
    const unsigned short* __restrict__ vpT,
    float* __restrict__ Opart, float* __restrict__ mpart, float* __restrict__ lpart,
    float* __restrict__ dout, int klen)
{
  __shared__ unsigned short Kl[64][72];
  __shared__ unsigned short Vt[64][72];
  __shared__ unsigned short Pl[4][16][72];

  const int tid = threadIdx.x, w = tid >> 6, l = tid & 63;
  const int lr = l & 15, lg = l >> 4;
  const int b = blockIdx.y, sp = blockIdx.z;
  const size_t boff = (size_t)b * SEQ * DV;
  const int qbase = blockIdx.x * 64 + w * 16;     // row within batch
  const int kstart = sp * klen;

  // Q fragments (A-operand): row = lr, k(d) = ks*32 + lg*8 .. +7
  s16x8 qf[2];
  #pragma unroll
  for (int ks = 0; ks < 2; ++ks)
    qf[ks] = *(const s16x8*)(qp + boff + (size_t)(qbase + lr) * DV + ks * 32 + lg * 8);

  f32x4 oacc[4] = {};
  float mrow[4], lrow[4];
  #pragma unroll
  for (int r = 0; r < 4; ++r) { mrow[r] = -1e30f; lrow[r] = 0.0f; }

  for (int kb = kstart; kb < kstart + klen; kb += 64) {
    __syncthreads();   // prior iter's K/V reads done before restage
    const unsigned short* kg = kp + boff + (size_t)kb * DV;
    const unsigned short* vg = vpT + boff + kb;   // element (d, j): vg + d*SEQ + j
    #pragma unroll
    for (int pass = 0; pass < 2; ++pass) {
      const int idx = pass * 256 + tid;
      const int row = idx >> 3, j8 = (idx & 7) * 8;
      *(s16x8*)&Kl[row][j8] = *(const s16x8*)(kg + row * DV + j8);
      *(s16x8*)&Vt[row][j8] = *(const s16x8*)(vg + (size_t)row * SEQ + j8);
    }
    __syncthreads();

    // S = Q K^T  (C layout: col=key=lr within ntile, row=q=lg*4+r)
    f32x4 sacc[4] = {};
    #pragma unroll
    for (int ks = 0; ks < 2; ++ks) {
      #pragma unroll
      for (int nt = 0; nt < 4; ++nt) {
        const s16x8 bfm = *(const s16x8*)&Kl[nt * 16 + lr][ks * 32 + lg * 8];
        sacc[nt] = MFMA_BF16(qf[ks], bfm, sacc[nt]);
      }
    }

    // online softmax per q-row (rows lg*4+r, keys across 16 lanes x 4 ntiles)
    #pragma unroll
    for (int r = 0; r < 4; ++r) {
      float mx = fmaxf(fmaxf(sacc[0][r], sacc[1][r]), fmaxf(sacc[2][r], sacc[3][r]));
      #pragma unroll
      for (int sh = 1; sh < 16; sh <<= 1) mx = fmaxf(mx, __shfl_xor(mx, sh));
      const float mnew = fmaxf(mrow[r], mx);
      const float corr = exp2f((mrow[r] - mnew) * 1.44269504f);
      lrow[r] *= corr;
      #pragma unroll
      for (int nt = 0; nt < 4; ++nt) oacc[nt][r] *= corr;
      float ps = 0.0f;
      #pragma unroll
      for (int nt = 0; nt < 4; ++nt) {
        const float p = exp2f((sacc[nt][r] - mnew) * 1.44269504f);
        sacc[nt][r] = p; ps += p;
      }
      #pragma unroll
      for (int sh = 1; sh < 16; sh <<= 1) ps += __shfl_xor(ps, sh);
      lrow[r] += ps;
      mrow[r] = mnew;
    }

    // P -> per-wave LDS (bf16), re-layout for A-operand. Wave-private:
    // no __syncthreads needed (DS ops in-order within a wave).
    #pragma unroll
    for (int nt = 0; nt < 4; ++nt)
      #pragma unroll
      for (int r = 0; r < 4; ++r)
        Pl[w][lg * 4 + r][nt * 16 + lr] = f2bf(sacc[nt][r]);

    // O += P V   (A: row=q=lr, k=key; B: k=key, col=d)
    #pragma unroll
    for (int ks = 0; ks < 2; ++ks) {
      const s16x8 af = *(const s16x8*)&Pl[w][lr][ks * 32 + lg * 8];
      #pragma unroll
      for (int nt = 0; nt < 4; ++nt) {
        const s16x8 bfm = *(const s16x8*)&Vt[nt * 16 + lr][ks * 32 + lg * 8];
        oacc[nt] = MFMA_BF16(af, bfm, oacc[nt]);
      }
    }
  }

  if (dout) {
    float rl[4];
    #pragma unroll
    for (int r = 0; r < 4; ++r) rl[r] = 1.0f / lrow[r];
    #pragma unroll
    for (int nt = 0; nt < 4; ++nt)
      #pragma unroll
      for (int r = 0; r < 4; ++r) {
        const int row = qbase + lg * 4 + r;
        dout[boff + (size_t)row * DV + nt * 16 + lr] = oacc[nt][r] * rl[r];
      }
  } else {
    const size_t po = ((size_t)sp * B_ + b) * SEQ * DV;
    #pragma unroll
    for (int nt = 0; nt < 4; ++nt)
      #pragma unroll
      for (int r = 0; r < 4; ++r) {
        const int row = qbase + lg * 4 + r;
        Opart[po + (size_t)row * DV + nt * 16 + lr] = oacc[nt][r];
      }
    if (lr == 0) {
      const size_t mo = ((size_t)sp * B_ + b) * SEQ + qbase + lg * 4;
      #pragma unroll
      for (int r = 0; r < 4; ++r) { mpart[mo + r] = mrow[r]; lpart[mo + r] = lrow[r]; }
    }
  }
}

// ---------------------------------------------------------------------------
// Combine: out = sum_sp exp(m_sp - M) * O_sp / sum_sp exp(m_sp - M) * l_sp
// One thread per float4 of output (4M f32 total).
// ---------------------------------------------------------------------------
__global__ __launch_bounds__(256) void combine_kernel(
    const float* __restrict__ Opart, const float* __restrict__ mpart,
    const float* __restrict__ lpart, float* __restrict__ out, int nsplit)
{
  const int g = blockIdx.x * 256 + threadIdx.x;   // float4 index
  const int row = g >> 4;                          // b*SEQ + s
  const int c4 = g & 15;
  const size_t rstride = (size_t)B_ * SEQ;

  float M = -1e30f;
  for (int sp = 0; sp < nsplit; ++sp) M = fmaxf(M, mpart[sp * rstride + row]);
  float denom = 0.0f;
  for (int sp = 0; sp < nsplit; ++sp)
    denom += lpart[sp * rstride + row] * exp2f((mpart[sp * rstride + row] - M) * 1.44269504f);

  f32x4 o = {};
  for (int sp = 0; sp < nsplit; ++sp) {
    const float wgt = exp2f((mpart[sp * rstride + row] - M) * 1.44269504f);
    const f32x4 op = *(const f32x4*)&Opart[sp * rstride * DV + (size_t)row * DV + c4 * 4];
    o += wgt * op;
  }
  const float inv = 1.0f / denom;
  *(f32x4*)&out[(size_t)row * DV + c4 * 4] = o * inv;
}

extern "C" void kernel_launch(void* const* d_in, const int* in_sizes, int n_in,
                              void* d_out, int out_size, void* d_ws, size_t ws_size,
                              hipStream_t stream) {
  const float* q_in = (const float*)d_in[0];
  const float* k_in = (const float*)d_in[1];
  const float* v_in = (const float*)d_in[2];
  const float* Wq   = (const float*)d_in[3];
  const float* bq   = (const float*)d_in[4];
  const float* Wk   = (const float*)d_in[5];
  const float* bk   = (const float*)d_in[6];
  const float* Wv   = (const float*)d_in[7];
  const float* bv   = (const float*)d_in[8];

  const size_t nproj = (size_t)B_ * SEQ * DV;           // elements per projection
  unsigned short* qp  = (unsigned short*)d_ws;
  unsigned short* kp  = qp + nproj;
  unsigned short* vpT = kp + nproj;
  char* after = (char*)(vpT + nproj);
  const size_t used_base = (size_t)((char*)after - (char*)d_ws);

  // pick largest nsplit in {4,2,1} whose partials fit ws
  int nsplit = 4;
  while (nsplit > 1) {
    const size_t need = used_base + (size_t)nsplit * B_ * SEQ * (DV * 4 + 8);
    if (need <= ws_size) break;
    nsplit >>= 1;
  }
  const bool direct = (nsplit == 1) &&
      (used_base + (size_t)B_ * SEQ * (DV * 4 + 8) > ws_size);

  float* Opart = (float*)after;
  float* mpart = Opart + (size_t)nsplit * B_ * SEQ * DV;
  float* lpart = mpart + (size_t)nsplit * B_ * SEQ;
  float* out = (float*)d_out;

  proj_kernel<<<dim3(256), dim3(256), 0, stream>>>(
      q_in, k_in, v_in, Wq, bq, Wk, bk, Wv, bv, qp, kp, vpT);

  attn_split_kernel<<<dim3(SEQ / 64, B_, nsplit), dim3(256), 0, stream>>>(
      qp, kp, vpT, direct ? nullptr : Opart, mpart, lpart,
      direct ? out : nullptr, SEQ / nsplit);

  if (!direct) {
    combine_kernel<<<dim3(B_ * SEQ * DV / 4 / 256), dim3(256), 0, stream>>>(
        Opart, mpart, lpart, out, nsplit);
  }
}

// Round 3
// 67.395 us; speedup vs baseline: 2.2025x; 1.3306x over previous
//
#include <hip/hip_runtime.h>
#include <hip/hip_bf16.h>

// Attention_15564961480846: q/k/v projections + softmax(QK^T/8)V
// B=4, S=4096, D_MODEL=128, d_k=d_v=64.
// Round 2: swapped-operand 32x32 MFMA flash attention (m214/T12 structure):
//  - S^T = mfma(K,Q): P-row lane-local -> in-register softmax (1 shfl_xor(32))
//  - O^T = mfma(V^T, P^T): rescale/normalize lane-uniform; V^T read as A-op
//  - cvt_pk_bf16 + lane^32 exchange for P -> MFMA B-operand
//  - K/V^T LDS tiles XOR-swizzled ((row&7)<<4): 32-way -> 4-way conflicts
//  - T14-lite async staging: global->reg issued before compute, LDS write after
//  - KV-split (nsplit up to 8) + combine pass for occupancy

using f32x4  = __attribute__((ext_vector_type(4)))  float;
using f32x16 = __attribute__((ext_vector_type(16))) float;
using s16x8  = __attribute__((ext_vector_type(8)))  short;

#define MFMA16(a, b, c) __builtin_amdgcn_mfma_f32_16x16x32_bf16((a), (b), (c), 0, 0, 0)
#define MFMA32(a, b, c) __builtin_amdgcn_mfma_f32_32x32x16_bf16((a), (b), (c), 0, 0, 0)

constexpr int SEQ = 4096;
constexpr int DM  = 128;
constexpr int DV  = 64;
constexpr int B_  = 4;
constexpr float LOG2E = 1.44269504f;

static __device__ __forceinline__ unsigned short f2bf(float f) {
  union { float f; unsigned u; } x; x.f = f;
  unsigned r = x.u + 0x7fffu + ((x.u >> 16) & 1u);   // RNE
  return (unsigned short)(r >> 16);
}

static __device__ __forceinline__ unsigned cvt_pk_bf16(float lo, float hi) {
  unsigned d;
  asm("v_cvt_pk_bf16_f32 %0, %1, %2" : "=v"(d) : "v"(lo), "v"(hi));
  return d;
}

// ---------------------------------------------------------------------------
// Projection (unchanged from round 1): bf16 outputs; q scaled 1/8; V stored
// transposed vpT[b][d][s].
// ---------------------------------------------------------------------------
__global__ __launch_bounds__(256) void proj_kernel(
    const float* __restrict__ q_in, const float* __restrict__ k_in,
    const float* __restrict__ v_in,
    const float* __restrict__ Wq, const float* __restrict__ bq,
    const float* __restrict__ Wk, const float* __restrict__ bk,
    const float* __restrict__ Wv, const float* __restrict__ bv,
    unsigned short* __restrict__ qp, unsigned short* __restrict__ kp,
    unsigned short* __restrict__ vpT)
{
  __shared__ unsigned short Wt[3][64][136];
  const int tid = threadIdx.x;
  {
    const float* Ws[3] = {Wq, Wk, Wv};
    for (int m = 0; m < 3; ++m) {
      const float* W = Ws[m];
      for (int idx = tid; idx < DM * DV; idx += 256) {
        const int k = idx >> 6, c = idx & 63;
        Wt[m][c][k] = f2bf(W[idx]);
      }
    }
  }
  __syncthreads();

  const int w = tid >> 6, l = tid & 63;
  const int lr = l & 15, lg = l >> 4;
  const int rowbase = blockIdx.x * 64 + w * 16;

  const float* ins[3] = {q_in, k_in, v_in};
  const float* bs[3]  = {bq, bk, bv};

  for (int m = 0; m < 3; ++m) {
    const float* in = ins[m];
    f32x4 acc[4] = {};
    #pragma unroll
    for (int ks = 0; ks < 4; ++ks) {
      const float* ap = in + (size_t)(rowbase + lr) * DM + ks * 32 + lg * 8;
      const float4 a0 = *(const float4*)ap;
      const float4 a1 = *(const float4*)(ap + 4);
      s16x8 af;
      af[0] = (short)f2bf(a0.x); af[1] = (short)f2bf(a0.y);
      af[2] = (short)f2bf(a0.z); af[3] = (short)f2bf(a0.w);
      af[4] = (short)f2bf(a1.x); af[5] = (short)f2bf(a1.y);
      af[6] = (short)f2bf(a1.z); af[7] = (short)f2bf(a1.w);
      #pragma unroll
      for (int nt = 0; nt < 4; ++nt) {
        const s16x8 bfm = *(const s16x8*)&Wt[m][nt * 16 + lr][ks * 32 + lg * 8];
        acc[nt] = MFMA16(af, bfm, acc[nt]);
      }
    }
    const float* bias = bs[m];
    const float scale = (m == 0) ? 0.125f : 1.0f;
    #pragma unroll
    for (int nt = 0; nt < 4; ++nt) {
      const int col = nt * 16 + lr;
      const float bb = bias[col];
      #pragma unroll
      for (int r = 0; r < 4; ++r) {
        const int row = rowbase + lg * 4 + r;
        const unsigned short val = f2bf((acc[nt][r] + bb) * scale);
        if (m == 0)      qp[(size_t)row * DV + col] = val;
        else if (m == 1) kp[(size_t)row * DV + col] = val;
        else             vpT[((size_t)(row >> 12) * DV + col) * SEQ + (row & (SEQ - 1))] = val;
      }
    }
  }
}

// ---------------------------------------------------------------------------
// Swapped 32x32 flash attention over key slice [sp*klen, (sp+1)*klen).
// Block = 4 waves; wave owns 32 q-rows (QBLK=128). KV tile = 64.
// ---------------------------------------------------------------------------
static __device__ __forceinline__ s16x8 lds_read_sw(const unsigned short* base,
                                                    int row, int cb) {
  return *(const s16x8*)((const char*)base + row * 128 + (cb ^ ((row & 7) << 4)));
}

__global__ __launch_bounds__(256) void attn_split_kernel(
    const unsigned short* __restrict__ qp, const unsigned short* __restrict__ kp,
    const unsigned short* __restrict__ vpT,
    float* __restrict__ Opart, float* __restrict__ mpart, float* __restrict__ lpart,
    float* __restrict__ dout, int klen)
{
  __shared__ unsigned short Kl[64 * 64];   // [key][d], swizzled rows of 128B
  __shared__ unsigned short Vt[64 * 64];   // [d][key], swizzled rows of 128B

  const int tid = threadIdx.x, wq = tid >> 6, l = tid & 63;
  const int l31 = l & 31, hi = l >> 5;
  const int b = blockIdx.y, sp = blockIdx.z;
  const size_t boff = (size_t)b * SEQ * DV;
  const int qrow = blockIdx.x * 128 + wq * 32 + l31;   // this lane's q
  const int kstart = sp * klen, kend = kstart + klen;

  // Q B-operand fragments: col=q=l31, k(d) = 16*ks + 8*hi + j
  s16x8 qf[4];
  {
    const unsigned short* qpr = qp + boff + (size_t)qrow * DV;
    #pragma unroll
    for (int ks = 0; ks < 4; ++ks)
      qf[ks] = *(const s16x8*)(qpr + 16 * ks + 8 * hi);
  }

  // staging: thread handles (row = it*32 + tid>>3, 16B chunk = tid&7)
  const int srow = tid >> 3, scol = (tid & 7) * 16;
  const unsigned short* kgb = kp + boff;
  const unsigned short* vgb = vpT + boff;
  s16x8 kr[2], vr[2];
  #pragma unroll
  for (int it = 0; it < 2; ++it) {
    const int row = it * 32 + srow;
    kr[it] = *(const s16x8*)(kgb + (size_t)(kstart + row) * DV + (scol >> 1));
    vr[it] = *(const s16x8*)(vgb + (size_t)row * SEQ + kstart + (scol >> 1));
  }

  f32x16 oacc[2] = {};
  float m = -1e30f, lsum = 0.0f;

  for (int kb = kstart; kb < kend; kb += 64) {
    __syncthreads();   // prior tile's LDS reads complete
    #pragma unroll
    for (int it = 0; it < 2; ++it) {
      const int row = it * 32 + srow;
      const int sw = scol ^ ((row & 7) << 4);
      *(s16x8*)((char*)Kl + row * 128 + sw) = kr[it];
      *(s16x8*)((char*)Vt + row * 128 + sw) = vr[it];
    }
    __syncthreads();   // tile visible

    // issue next tile's loads (hidden under compute)
    if (kb + 64 < kend) {
      #pragma unroll
      for (int it = 0; it < 2; ++it) {
        const int row = it * 32 + srow;
        kr[it] = *(const s16x8*)(kgb + (size_t)(kb + 64 + row) * DV + (scol >> 1));
        vr[it] = *(const s16x8*)(vgb + (size_t)row * SEQ + kb + 64 + (scol >> 1));
      }
    }

    // S^T = K Q^T : sacc[mt] covers keys 32*mt..+31 for q = l31
    f32x16 sacc[2] = {};
    #pragma unroll
    for (int ks = 0; ks < 4; ++ks) {
      const int cb = 32 * ks + 16 * hi;
      const s16x8 kf0 = lds_read_sw(Kl, l31, cb);
      const s16x8 kf1 = lds_read_sw(Kl, 32 + l31, cb);
      sacc[0] = MFMA32(kf0, qf[ks], sacc[0]);
      sacc[1] = MFMA32(kf1, qf[ks], sacc[1]);
    }

    // in-register online softmax (row = own q, lane-local)
    float pm = -1e30f;
    #pragma unroll
    for (int mt = 0; mt < 2; ++mt)
      #pragma unroll
      for (int i = 0; i < 16; ++i) pm = fmaxf(pm, sacc[mt][i]);
    pm = fmaxf(pm, __shfl_xor(pm, 32));

    if (!__all(pm <= m + 8.0f)) {          // defer-max (T13, THR=8)
      const float mnew = fmaxf(m, pm);
      const float corr = exp2f((m - mnew) * LOG2E);
      lsum *= corr;
      #pragma unroll
      for (int mt = 0; mt < 2; ++mt)
        #pragma unroll
        for (int i = 0; i < 16; ++i) oacc[mt][i] *= corr;
      m = mnew;
    }
    const float mb = m * LOG2E;
    float ps = 0.0f;
    #pragma unroll
    for (int mt = 0; mt < 2; ++mt)
      #pragma unroll
      for (int i = 0; i < 16; ++i) {
        const float p = exp2f(sacc[mt][i] * LOG2E - mb);
        sacc[mt][i] = p; ps += p;
      }
    ps += __shfl_xor(ps, 32);
    lsum += ps;

    // P^T -> bf16 B-operand fragments + PV (O^T += V^T P^T)
    #pragma unroll
    for (int ki = 0; ki < 4; ++ki) {
      const int mt = ki >> 1, w8 = (ki & 1) * 8;
      const unsigned x0 = cvt_pk_bf16(sacc[mt][w8 + 0], sacc[mt][w8 + 1]);
      const unsigned x1 = cvt_pk_bf16(sacc[mt][w8 + 2], sacc[mt][w8 + 3]);
      const unsigned y0 = cvt_pk_bf16(sacc[mt][w8 + 4], sacc[mt][w8 + 5]);
      const unsigned y1 = cvt_pk_bf16(sacc[mt][w8 + 6], sacc[mt][w8 + 7]);
      const unsigned tx0 = __shfl_xor((int)x0, 32), tx1 = __shfl_xor((int)x1, 32);
      const unsigned ty0 = __shfl_xor((int)y0, 32), ty1 = __shfl_xor((int)y1, 32);
      union { unsigned u[4]; s16x8 v; } pf;
      pf.u[0] = hi ? ty0 : x0;
      pf.u[1] = hi ? ty1 : x1;
      pf.u[2] = hi ? y0  : tx0;
      pf.u[3] = hi ? y1  : tx1;
      const int cb = 32 * ki + 16 * hi;
      const s16x8 vf0 = lds_read_sw(Vt, l31, cb);
      const s16x8 vf1 = lds_read_sw(Vt, 32 + l31, cb);
      oacc[0] = MFMA32(vf0, pf.v, oacc[0]);
      oacc[1] = MFMA32(vf1, pf.v, oacc[1]);
    }
  }

  // write out: O^T lane holds col q = l31 (own q!), rows d = crow(r,hi)+32*mt
  if (dout) {
    const float rinv = 1.0f / lsum;
    float* op = dout + boff + (size_t)qrow * DV;
    #pragma unroll
    for (int mt = 0; mt < 2; ++mt)
      #pragma unroll
      for (int g = 0; g < 4; ++g) {
        const int d0 = 32 * mt + 8 * g + 4 * hi;
        float4 v4;
        v4.x = oacc[mt][4 * g + 0] * rinv; v4.y = oacc[mt][4 * g + 1] * rinv;
        v4.z = oacc[mt][4 * g + 2] * rinv; v4.w = oacc[mt][4 * g + 3] * rinv;
        *(float4*)(op + d0) = v4;
      }
  } else {
    const size_t po = ((size_t)sp * B_ + b) * SEQ * DV;
    float* op = Opart + po + (size_t)qrow * DV;
    #pragma unroll
    for (int mt = 0; mt < 2; ++mt)
      #pragma unroll
      for (int g = 0; g < 4; ++g) {
        const int d0 = 32 * mt + 8 * g + 4 * hi;
        float4 v4;
        v4.x = oacc[mt][4 * g + 0]; v4.y = oacc[mt][4 * g + 1];
        v4.z = oacc[mt][4 * g + 2]; v4.w = oacc[mt][4 * g + 3];
        *(float4*)(op + d0) = v4;
      }
    if (l < 32) {
      const size_t mo = ((size_t)sp * B_ + b) * SEQ + blockIdx.x * 128 + wq * 32 + l;
      mpart[mo] = m; lpart[mo] = lsum;
    }
  }
}

// ---------------------------------------------------------------------------
// Combine partials (unchanged from round 1).
// ---------------------------------------------------------------------------
__global__ __launch_bounds__(256) void combine_kernel(
    const float* __restrict__ Opart, const float* __restrict__ mpart,
    const float* __restrict__ lpart, float* __restrict__ out, int nsplit)
{
  const int g = blockIdx.x * 256 + threadIdx.x;
  const int row = g >> 4;
  const int c4 = g & 15;
  const size_t rstride = (size_t)B_ * SEQ;

  float M = -1e30f;
  for (int sp = 0; sp < nsplit; ++sp) M = fmaxf(M, mpart[sp * rstride + row]);
  float denom = 0.0f;
  for (int sp = 0; sp < nsplit; ++sp)
    denom += lpart[sp * rstride + row] * exp2f((mpart[sp * rstride + row] - M) * LOG2E);

  f32x4 o = {};
  for (int sp = 0; sp < nsplit; ++sp) {
    const float wgt = exp2f((mpart[sp * rstride + row] - M) * LOG2E);
    const f32x4 op = *(const f32x4*)&Opart[sp * rstride * DV + (size_t)row * DV + c4 * 4];
    o += wgt * op;
  }
  const float inv = 1.0f / denom;
  *(f32x4*)&out[(size_t)row * DV + c4 * 4] = o * inv;
}

extern "C" void kernel_launch(void* const* d_in, const int* in_sizes, int n_in,
                              void* d_out, int out_size, void* d_ws, size_t ws_size,
                              hipStream_t stream) {
  const float* q_in = (const float*)d_in[0];
  const float* k_in = (const float*)d_in[1];
  const float* v_in = (const float*)d_in[2];
  const float* Wq   = (const float*)d_in[3];
  const float* bq   = (const float*)d_in[4];
  const float* Wk   = (const float*)d_in[5];
  const float* bk   = (const float*)d_in[6];
  const float* Wv   = (const float*)d_in[7];
  const float* bv   = (const float*)d_in[8];

  const size_t nproj = (size_t)B_ * SEQ * DV;
  unsigned short* qp  = (unsigned short*)d_ws;
  unsigned short* kp  = qp + nproj;
  unsigned short* vpT = kp + nproj;
  char* after = (char*)(vpT + nproj);
  const size_t used_base = (size_t)((char*)after - (char*)d_ws);

  // pick largest nsplit in {8,4,2,1} whose partials fit ws
  int nsplit = 8;
  while (nsplit > 1) {
    const size_t need = used_base + (size_t)nsplit * B_ * SEQ * (DV * 4 + 8);
    if (need <= ws_size) break;
    nsplit >>= 1;
  }
  const bool direct = (nsplit == 1) &&
      (used_base + (size_t)B_ * SEQ * (DV * 4 + 8) > ws_size);

  float* Opart = (float*)after;
  float* mpart = Opart + (size_t)nsplit * B_ * SEQ * DV;
  float* lpart = mpart + (size_t)nsplit * B_ * SEQ;
  float* out = (float*)d_out;

  proj_kernel<<<dim3(256), dim3(256), 0, stream>>>(
      q_in, k_in, v_in, Wq, bq, Wk, bk, Wv, bv, qp, kp, vpT);

  attn_split_kernel<<<dim3(SEQ / 128, B_, nsplit), dim3(256), 0, stream>>>(
      qp, kp, vpT, direct ? nullptr : Opart, mpart, lpart,
      direct ? out : nullptr, SEQ / nsplit);

  if (!direct) {
    combine_kernel<<<dim3(B_ * SEQ * DV / 4 / 256), dim3(256), 0, stream>>>(
        Opart, mpart, lpart, out, nsplit);
  }
}

// Round 5
// 65.977 us; speedup vs baseline: 2.2499x; 1.0215x over previous
//
#include <hip/hip_runtime.h>
#include <hip/hip_bf16.h>

// Attention_15564961480846: q/k/v projections + softmax(QK^T/8)V
// B=4, S=4096, D_MODEL=128, d_k=d_v=64.
// Round 4: round 3's structure (double-buffered K/V -> 1 barrier/tile, tree
// reductions, setprio, launch_bounds(256,4)) with the lane-exchange reverted
// to round 2's PROVEN __shfl_xor forms (permlane asm was the r3 correctness bug).

using f32x4  = __attribute__((ext_vector_type(4)))  float;
using f32x16 = __attribute__((ext_vector_type(16))) float;
using s16x8  = __attribute__((ext_vector_type(8)))  short;

#define MFMA16(a, b, c) __builtin_amdgcn_mfma_f32_16x16x32_bf16((a), (b), (c), 0, 0, 0)
#define MFMA32(a, b, c) __builtin_amdgcn_mfma_f32_32x32x16_bf16((a), (b), (c), 0, 0, 0)

constexpr int SEQ = 4096;
constexpr int DM  = 128;
constexpr int DV  = 64;
constexpr int B_  = 4;
constexpr float LOG2E = 1.44269504f;

static __device__ __forceinline__ unsigned short f2bf(float f) {
  union { float f; unsigned u; } x; x.f = f;
  unsigned r = x.u + 0x7fffu + ((x.u >> 16) & 1u);   // RNE
  return (unsigned short)(r >> 16);
}

static __device__ __forceinline__ unsigned cvt_pk_bf16(float lo, float hi) {
  unsigned d;
  asm("v_cvt_pk_bf16_f32 %0, %1, %2" : "=v"(d) : "v"(lo), "v"(hi));
  return d;
}

// ---------------------------------------------------------------------------
// Projection: bf16 outputs; q scaled 1/8; V stored transposed vpT[b][d][s].
// ---------------------------------------------------------------------------
__global__ __launch_bounds__(256) void proj_kernel(
    const float* __restrict__ q_in, const float* __restrict__ k_in,
    const float* __restrict__ v_in,
    const float* __restrict__ Wq, const float* __restrict__ bq,
    const float* __restrict__ Wk, const float* __restrict__ bk,
    const float* __restrict__ Wv, const float* __restrict__ bv,
    unsigned short* __restrict__ qp, unsigned short* __restrict__ kp,
    unsigned short* __restrict__ vpT)
{
  __shared__ unsigned short Wt[3][64][136];
  const int tid = threadIdx.x;
  {
    const float* Ws[3] = {Wq, Wk, Wv};
    for (int m = 0; m < 3; ++m) {
      const float* W = Ws[m];
      for (int idx = tid; idx < DM * DV; idx += 256) {
        const int k = idx >> 6, c = idx & 63;
        Wt[m][c][k] = f2bf(W[idx]);
      }
    }
  }
  __syncthreads();

  const int w = tid >> 6, l = tid & 63;
  const int lr = l & 15, lg = l >> 4;
  const int rowbase = blockIdx.x * 64 + w * 16;

  const float* ins[3] = {q_in, k_in, v_in};
  const float* bs[3]  = {bq, bk, bv};

  for (int m = 0; m < 3; ++m) {
    const float* in = ins[m];
    f32x4 acc[4] = {};
    #pragma unroll
    for (int ks = 0; ks < 4; ++ks) {
      const float* ap = in + (size_t)(rowbase + lr) * DM + ks * 32 + lg * 8;
      const float4 a0 = *(const float4*)ap;
      const float4 a1 = *(const float4*)(ap + 4);
      s16x8 af;
      af[0] = (short)f2bf(a0.x); af[1] = (short)f2bf(a0.y);
      af[2] = (short)f2bf(a0.z); af[3] = (short)f2bf(a0.w);
      af[4] = (short)f2bf(a1.x); af[5] = (short)f2bf(a1.y);
      af[6] = (short)f2bf(a1.z); af[7] = (short)f2bf(a1.w);
      #pragma unroll
      for (int nt = 0; nt < 4; ++nt) {
        const s16x8 bfm = *(const s16x8*)&Wt[m][nt * 16 + lr][ks * 32 + lg * 8];
        acc[nt] = MFMA16(af, bfm, acc[nt]);
      }
    }
    const float* bias = bs[m];
    const float scale = (m == 0) ? 0.125f : 1.0f;
    #pragma unroll
    for (int nt = 0; nt < 4; ++nt) {
      const int col = nt * 16 + lr;
      const float bb = bias[col];
      #pragma unroll
      for (int r = 0; r < 4; ++r) {
        const int row = rowbase + lg * 4 + r;
        const unsigned short val = f2bf((acc[nt][r] + bb) * scale);
        if (m == 0)      qp[(size_t)row * DV + col] = val;
        else if (m == 1) kp[(size_t)row * DV + col] = val;
        else             vpT[((size_t)(row >> 12) * DV + col) * SEQ + (row & (SEQ - 1))] = val;
      }
    }
  }
}

// ---------------------------------------------------------------------------
// Swapped 32x32 flash attention over key slice [sp*klen, (sp+1)*klen).
// Block = 4 waves; wave owns 32 q-rows (QBLK=128). KV tile = 64, double-buffered.
// ---------------------------------------------------------------------------
static __device__ __forceinline__ s16x8 lds_read_sw(const unsigned short* base,
                                                    int row, int cb) {
  return *(const s16x8*)((const char*)base + row * 128 + (cb ^ ((row & 7) << 4)));
}

__global__ __launch_bounds__(256, 4) void attn_split_kernel(
    const unsigned short* __restrict__ qp, const unsigned short* __restrict__ kp,
    const unsigned short* __restrict__ vpT,
    float* __restrict__ Opart, float* __restrict__ mpart, float* __restrict__ lpart,
    float* __restrict__ dout, int klen)
{
  __shared__ unsigned short Kl[2][64 * 64];   // [buf][key][d], swizzled 128B rows
  __shared__ unsigned short Vt[2][64 * 64];   // [buf][d][key], swizzled 128B rows

  const int tid = threadIdx.x, wq = tid >> 6, l = tid & 63;
  const int l31 = l & 31, hi = l >> 5;
  const int b = blockIdx.y, sp = blockIdx.z;
  const size_t boff = (size_t)b * SEQ * DV;
  const int qrow = blockIdx.x * 128 + wq * 32 + l31;   // this lane's q
  const int kstart = sp * klen, kend = kstart + klen;

  // Q B-operand fragments: col=q=l31, k(d) = 16*ks + 8*hi + j
  s16x8 qf[4];
  {
    const unsigned short* qpr = qp + boff + (size_t)qrow * DV;
    #pragma unroll
    for (int ks = 0; ks < 4; ++ks)
      qf[ks] = *(const s16x8*)(qpr + 16 * ks + 8 * hi);
  }

  // staging mapping: row = it*32 + (tid>>3), 16B chunk = (tid&7)*16 bytes
  const int srow = tid >> 3, scol = (tid & 7) * 16;
  const int swz = scol ^ ((srow & 7) << 4);   // (row&7)==(srow&7) for both its
  const unsigned short* kgb = kp + boff;
  const unsigned short* vgb = vpT + boff;

  s16x8 kr[2], vr[2];
  #pragma unroll
  for (int it = 0; it < 2; ++it) {
    const int row = it * 32 + srow;
    kr[it] = *(const s16x8*)(kgb + (size_t)(kstart + row) * DV + (scol >> 1));
    vr[it] = *(const s16x8*)(vgb + (size_t)row * SEQ + kstart + (scol >> 1));
  }
  #pragma unroll
  for (int it = 0; it < 2; ++it) {
    const int row = it * 32 + srow;
    *(s16x8*)((char*)Kl[0] + row * 128 + swz) = kr[it];
    *(s16x8*)((char*)Vt[0] + row * 128 + swz) = vr[it];
  }
  __syncthreads();

  f32x16 oacc[2] = {};
  float m = -1e30f, lsum = 0.0f;
  int cur = 0;

  for (int kb = kstart; kb < kend; kb += 64) {
    const bool more = (kb + 64 < kend);
    // issue next tile's global loads early (hide under compute)
    if (more) {
      #pragma unroll
      for (int it = 0; it < 2; ++it) {
        const int row = it * 32 + srow;
        kr[it] = *(const s16x8*)(kgb + (size_t)(kb + 64 + row) * DV + (scol >> 1));
        vr[it] = *(const s16x8*)(vgb + (size_t)row * SEQ + kb + 64 + (scol >> 1));
      }
    }

    // S^T = K Q^T : sacc[mt] covers keys 32*mt..+31 for q = l31
    const unsigned short* Kc = Kl[cur];
    f32x16 sacc[2] = {};
    __builtin_amdgcn_s_setprio(1);
    #pragma unroll
    for (int ks = 0; ks < 4; ++ks) {
      const int cb = 32 * ks + 16 * hi;
      const s16x8 kf0 = lds_read_sw(Kc, l31, cb);
      const s16x8 kf1 = lds_read_sw(Kc, 32 + l31, cb);
      sacc[0] = MFMA32(kf0, qf[ks], sacc[0]);
      sacc[1] = MFMA32(kf1, qf[ks], sacc[1]);
    }
    __builtin_amdgcn_s_setprio(0);

    // ---- in-register online softmax, tree reductions (depth 5) ----
    float t16[16];
    #pragma unroll
    for (int i = 0; i < 16; ++i) t16[i] = fmaxf(sacc[0][i], sacc[1][i]);
    float t8[8];
    #pragma unroll
    for (int i = 0; i < 8; ++i) t8[i] = fmaxf(t16[i], t16[i + 8]);
    float t4[4];
    #pragma unroll
    for (int i = 0; i < 4; ++i) t4[i] = fmaxf(t8[i], t8[i + 4]);
    float pm = fmaxf(fmaxf(t4[0], t4[1]), fmaxf(t4[2], t4[3]));
    pm = fmaxf(pm, __shfl_xor(pm, 32));

    if (!__all(pm <= m + 8.0f)) {          // defer-max (T13, THR=8)
      const float mnew = fmaxf(m, pm);
      const float corr = exp2f((m - mnew) * LOG2E);
      lsum *= corr;
      #pragma unroll
      for (int mt = 0; mt < 2; ++mt)
        #pragma unroll
        for (int i = 0; i < 16; ++i) oacc[mt][i] *= corr;
      m = mnew;
    }
    #pragma unroll
    for (int mt = 0; mt < 2; ++mt)
      #pragma unroll
      for (int i = 0; i < 16; ++i)
        sacc[mt][i] = exp2f((sacc[mt][i] - m) * LOG2E);
    float s16s[16];
    #pragma unroll
    for (int i = 0; i < 16; ++i) s16s[i] = sacc[0][i] + sacc[1][i];
    float s8[8];
    #pragma unroll
    for (int i = 0; i < 8; ++i) s8[i] = s16s[i] + s16s[i + 8];
    float s4[4];
    #pragma unroll
    for (int i = 0; i < 4; ++i) s4[i] = s8[i] + s8[i + 4];
    float ps = (s4[0] + s4[1]) + (s4[2] + s4[3]);
    ps += __shfl_xor(ps, 32);
    lsum += ps;

    // ---- P^T -> bf16 B-fragments (round-2-proven shfl_xor exchange) + PV ----
    const unsigned short* Vc = Vt[cur];
    __builtin_amdgcn_s_setprio(1);
    #pragma unroll
    for (int ki = 0; ki < 4; ++ki) {
      const int mt = ki >> 1, w8 = (ki & 1) * 8;
      const unsigned x0 = cvt_pk_bf16(sacc[mt][w8 + 0], sacc[mt][w8 + 1]);
      const unsigned x1 = cvt_pk_bf16(sacc[mt][w8 + 2], sacc[mt][w8 + 3]);
      const unsigned y0 = cvt_pk_bf16(sacc[mt][w8 + 4], sacc[mt][w8 + 5]);
      const unsigned y1 = cvt_pk_bf16(sacc[mt][w8 + 6], sacc[mt][w8 + 7]);
      const unsigned tx0 = __shfl_xor((int)x0, 32), tx1 = __shfl_xor((int)x1, 32);
      const unsigned ty0 = __shfl_xor((int)y0, 32), ty1 = __shfl_xor((int)y1, 32);
      union { unsigned u[4]; s16x8 v; } pf;
      pf.u[0] = hi ? ty0 : x0;
      pf.u[1] = hi ? ty1 : x1;
      pf.u[2] = hi ? y0  : tx0;
      pf.u[3] = hi ? y1  : tx1;
      const int cb = 32 * ki + 16 * hi;
      const s16x8 vf0 = lds_read_sw(Vc, l31, cb);
      const s16x8 vf1 = lds_read_sw(Vc, 32 + l31, cb);
      oacc[0] = MFMA32(vf0, pf.v, oacc[0]);
      oacc[1] = MFMA32(vf1, pf.v, oacc[1]);
    }
    __builtin_amdgcn_s_setprio(0);

    // ---- stage next tile into the other buffer, single barrier ----
    if (more) {
      #pragma unroll
      for (int it = 0; it < 2; ++it) {
        const int row = it * 32 + srow;
        *(s16x8*)((char*)Kl[cur ^ 1] + row * 128 + swz) = kr[it];
        *(s16x8*)((char*)Vt[cur ^ 1] + row * 128 + swz) = vr[it];
      }
      __syncthreads();
    }
    cur ^= 1;
  }

  // write out: lane holds col q = l31 (own q), rows d = 8*g + 4*hi + (0..3) + 32*mt
  if (dout) {
    const float rinv = 1.0f / lsum;
    float* op = dout + boff + (size_t)qrow * DV;
    #pragma unroll
    for (int mt = 0; mt < 2; ++mt)
      #pragma unroll
      for (int g = 0; g < 4; ++g) {
        const int d0 = 32 * mt + 8 * g + 4 * hi;
        float4 v4;
        v4.x = oacc[mt][4 * g + 0] * rinv; v4.y = oacc[mt][4 * g + 1] * rinv;
        v4.z = oacc[mt][4 * g + 2] * rinv; v4.w = oacc[mt][4 * g + 3] * rinv;
        *(float4*)(op + d0) = v4;
      }
  } else {
    const size_t po = ((size_t)sp * B_ + b) * SEQ * DV;
    float* op = Opart + po + (size_t)qrow * DV;
    #pragma unroll
    for (int mt = 0; mt < 2; ++mt)
      #pragma unroll
      for (int g = 0; g < 4; ++g) {
        const int d0 = 32 * mt + 8 * g + 4 * hi;
        float4 v4;
        v4.x = oacc[mt][4 * g + 0]; v4.y = oacc[mt][4 * g + 1];
        v4.z = oacc[mt][4 * g + 2]; v4.w = oacc[mt][4 * g + 3];
        *(float4*)(op + d0) = v4;
      }
    if (l < 32) {
      const size_t mo = ((size_t)sp * B_ + b) * SEQ + blockIdx.x * 128 + wq * 32 + l;
      mpart[mo] = m; lpart[mo] = lsum;
    }
  }
}

// ---------------------------------------------------------------------------
// Combine partials.
// ---------------------------------------------------------------------------
__global__ __launch_bounds__(256) void combine_kernel(
    const float* __restrict__ Opart, const float* __restrict__ mpart,
    const float* __restrict__ lpart, float* __restrict__ out, int nsplit)
{
  const int g = blockIdx.x * 256 + threadIdx.x;
  const int row = g >> 4;
  const int c4 = g & 15;
  const size_t rstride = (size_t)B_ * SEQ;

  float M = -1e30f;
  for (int sp = 0; sp < nsplit; ++sp) M = fmaxf(M, mpart[sp * rstride + row]);
  float denom = 0.0f;
  for (int sp = 0; sp < nsplit; ++sp)
    denom += lpart[sp * rstride + row] * exp2f((mpart[sp * rstride + row] - M) * LOG2E);

  f32x4 o = {};
  for (int sp = 0; sp < nsplit; ++sp) {
    const float wgt = exp2f((mpart[sp * rstride + row] - M) * LOG2E);
    const f32x4 op = *(const f32x4*)&Opart[sp * rstride * DV + (size_t)row * DV + c4 * 4];
    o += wgt * op;
  }
  const float inv = 1.0f / denom;
  *(f32x4*)&out[(size_t)row * DV + c4 * 4] = o * inv;
}

extern "C" void kernel_launch(void* const* d_in, const int* in_sizes, int n_in,
                              void* d_out, int out_size, void* d_ws, size_t ws_size,
                              hipStream_t stream) {
  const float* q_in = (const float*)d_in[0];
  const float* k_in = (const float*)d_in[1];
  const float* v_in = (const float*)d_in[2];
  const float* Wq   = (const float*)d_in[3];
  const float* bq   = (const float*)d_in[4];
  const float* Wk   = (const float*)d_in[5];
  const float* bk   = (const float*)d_in[6];
  const float* Wv   = (const float*)d_in[7];
  const float* bv   = (const float*)d_in[8];

  const size_t nproj = (size_t)B_ * SEQ * DV;
  unsigned short* qp  = (unsigned short*)d_ws;
  unsigned short* kp  = qp + nproj;
  unsigned short* vpT = kp + nproj;
  char* after = (char*)(vpT + nproj);
  const size_t used_base = (size_t)((char*)after - (char*)d_ws);

  // pick largest nsplit in {8,4,2,1} whose partials fit ws
  int nsplit = 8;
  while (nsplit > 1) {
    const size_t need = used_base + (size_t)nsplit * B_ * SEQ * (DV * 4 + 8);
    if (need <= ws_size) break;
    nsplit >>= 1;
  }
  const bool direct = (nsplit == 1) &&
      (used_base + (size_t)B_ * SEQ * (DV * 4 + 8) > ws_size);

  float* Opart = (float*)after;
  float* mpart = Opart + (size_t)nsplit * B_ * SEQ * DV;
  float* lpart = mpart + (size_t)nsplit * B_ * SEQ;
  float* out = (float*)d_out;

  proj_kernel<<<dim3(256), dim3(256), 0, stream>>>(
      q_in, k_in, v_in, Wq, bq, Wk, bk, Wv, bv, qp, kp, vpT);

  attn_split_kernel<<<dim3(SEQ / 128, B_, nsplit), dim3(256), 0, stream>>>(
      qp, kp, vpT, direct ? nullptr : Opart, mpart, lpart,
      direct ? out : nullptr, SEQ / nsplit);

  if (!direct) {
    combine_kernel<<<dim3(B_ * SEQ * DV / 4 / 256), dim3(256), 0, stream>>>(
        Opart, mpart, lpart, out, nsplit);
  }
}